// Round 5
// baseline (5012.017 us; speedup 1.0000x reference)
//
#include <hip/hip_runtime.h>
#include <hip/hip_bf16.h>

#define HID 2048
#define NH 64       // heads
#define HP 64       // head dim P
#define SN 128      // state dim N
#define KC 4        // conv kernel
#define LQ 4096     // sequence length
#define INTER 4096
#define CONV_DIM 4352   // INTER + 2*G*N
#define PROJ_D 8512     // INTER + CONV_DIM + NH
#define EPSV 1e-6f

// ---------------------------------------------------------------------------
// GEMM1: proj = hidden[LQ][HID] @ in_proj_w[PROJ_D][HID]^T, split fp32 out:
//   cols [0,4096) -> gate ; [4096,8448) -> convIn ; [8448,8512) -> dtraw
// ---------------------------------------------------------------------------
__global__ __launch_bounds__(256) void gemm1(const float* __restrict__ A,
                                             const float* __restrict__ B,
                                             float* __restrict__ gate,
                                             float* __restrict__ convIn,
                                             float* __restrict__ dtraw) {
    __shared__ float As[16][68];
    __shared__ float Bs[16][68];
    const int tx = threadIdx.x, ty = threadIdx.y;
    const int tid = ty * 16 + tx;
    const int m0 = blockIdx.y * 64, n0 = blockIdx.x * 64;
    const int lk = tid & 15, lr = tid >> 4;
    const int K = HID;

    float acc[4][4] = {};
    for (int k0 = 0; k0 < K; k0 += 16) {
#pragma unroll
        for (int i = 0; i < 4; i++) {
            As[lk][lr + i * 16] = A[(size_t)(m0 + lr + i * 16) * K + k0 + lk];
            Bs[lk][lr + i * 16] = B[(size_t)(n0 + lr + i * 16) * K + k0 + lk];
        }
        __syncthreads();
#pragma unroll
        for (int k = 0; k < 16; k++) {
            float4 a4 = *(const float4*)&As[k][ty * 4];
            float4 b4 = *(const float4*)&Bs[k][tx * 4];
            float av[4] = {a4.x, a4.y, a4.z, a4.w};
            float bv[4] = {b4.x, b4.y, b4.z, b4.w};
#pragma unroll
            for (int i = 0; i < 4; i++)
#pragma unroll
                for (int j = 0; j < 4; j++) acc[i][j] += av[i] * bv[j];
        }
        __syncthreads();
    }
    const int row = m0 + ty * 4;
    const int col = n0 + tx * 4;
#pragma unroll
    for (int i = 0; i < 4; i++) {
        float4 o = make_float4(acc[i][0], acc[i][1], acc[i][2], acc[i][3]);
        if (n0 < INTER) {
            *(float4*)&gate[(size_t)(row + i) * INTER + col] = o;
        } else if (n0 < INTER + CONV_DIM) {
            *(float4*)&convIn[(size_t)(row + i) * CONV_DIM + (col - INTER)] = o;
        } else {
            *(float4*)&dtraw[(size_t)(row + i) * NH + (col - INTER - CONV_DIM)] = o;
        }
    }
}

// ---------------------------------------------------------------------------
// Depthwise causal conv (K=4) + bias + silu.  fp32 -> fp32.
// out[t][c] = silu( cb[c] + sum_j convIn[t-3+j][c] * cw[c][j] )
// ---------------------------------------------------------------------------
__global__ __launch_bounds__(256) void conv_silu(const float* __restrict__ convIn,
                                                 const float* __restrict__ cw,
                                                 const float* __restrict__ cb,
                                                 float* __restrict__ hBC) {
    int id = blockIdx.x * 256 + threadIdx.x;      // over LQ*CONV_DIM, c fastest
    int c = id % CONV_DIM;
    int t = id / CONV_DIM;
    float acc = cb[c];
#pragma unroll
    for (int j = 0; j < KC; j++) {
        int tt = t - (KC - 1) + j;
        if (tt >= 0) acc += convIn[(size_t)tt * CONV_DIM + c] * cw[c * KC + j];
    }
    float sv = acc / (1.f + expf(-acc));
    hBC[(size_t)t * CONV_DIM + c] = sv;
}

// ---------------------------------------------------------------------------
// dt = softplus(dtraw + dt_bias);  dA = -exp(A_log) * dt   ([LQ][NH])
// ---------------------------------------------------------------------------
__global__ __launch_bounds__(256) void dt_kernel(const float* __restrict__ dtraw,
                                                 const float* __restrict__ dt_bias,
                                                 const float* __restrict__ A_log,
                                                 float* __restrict__ dtg,
                                                 float* __restrict__ dAg) {
    int g = blockIdx.x * 256 + threadIdx.x;   // LQ*NH
    int h = g & (NH - 1);
    float x = dtraw[g] + dt_bias[h];
    float dtv = (x > 20.f) ? x : log1pf(expf(x));
    dtg[g] = dtv;
    dAg[g] = -expf(A_log[h]) * dtv;
}

// ---------------------------------------------------------------------------
// Exact sequential SSD recurrence, one block per head h.
//   S_t[p][n] = exp(dA_t) * S_{t-1}[p][n] + dt_t * x_t[p] * B_t[n]
//   y_t[p]    = sum_n C_t[n] * S_t[p][n] + D[h] * x_t[p]
// 256 threads: thread = (p = tid>>2, quarter q = tid&3 -> n in [32q,32q+32)).
// ---------------------------------------------------------------------------
__global__ __launch_bounds__(256) void ssd_recur(const float* __restrict__ hBC,
                                                 const float* __restrict__ dtg,
                                                 const float* __restrict__ dAg,
                                                 const float* __restrict__ Dv,
                                                 float* __restrict__ y) {
    const int h = blockIdx.x;
    const int tid = threadIdx.x;
    const int p = tid >> 2, q = tid & 3, n0 = q * 32;

    __shared__ float Bs[32][SN];
    __shared__ float Csh[32][SN];
    __shared__ float xs[32][HP];
    __shared__ float es[32], dts[32];

    float S[32];
#pragma unroll
    for (int j = 0; j < 32; j++) S[j] = 0.f;
    const float Dh = Dv[h];

    for (int t0 = 0; t0 < LQ; t0 += 32) {
        __syncthreads();
        for (int i = tid; i < 32 * SN; i += 256) {
            int r = i >> 7, n = i & 127;
            size_t base = (size_t)(t0 + r) * CONV_DIM + INTER;
            Bs[r][n]  = hBC[base + n];
            Csh[r][n] = hBC[base + SN + n];
        }
        for (int i = tid; i < 32 * HP; i += 256) {
            int r = i >> 6, pp = i & 63;
            xs[r][pp] = hBC[(size_t)(t0 + r) * CONV_DIM + h * HP + pp];
        }
        if (tid < 32) {
            dts[tid] = dtg[(size_t)(t0 + tid) * NH + h];
            es[tid]  = expf(dAg[(size_t)(t0 + tid) * NH + h]);
        }
        __syncthreads();

        for (int i = 0; i < 32; i++) {
            const float e = es[i];
            const float w = dts[i] * xs[i][p];
            const float* Brow = &Bs[i][n0];
            const float* Crow = &Csh[i][n0];
            float yp0 = 0.f, yp1 = 0.f, yp2 = 0.f, yp3 = 0.f;
#pragma unroll
            for (int j = 0; j < 32; j += 4) {
                S[j + 0] = e * S[j + 0] + w * Brow[j + 0]; yp0 += Crow[j + 0] * S[j + 0];
                S[j + 1] = e * S[j + 1] + w * Brow[j + 1]; yp1 += Crow[j + 1] * S[j + 1];
                S[j + 2] = e * S[j + 2] + w * Brow[j + 2]; yp2 += Crow[j + 2] * S[j + 2];
                S[j + 3] = e * S[j + 3] + w * Brow[j + 3]; yp3 += Crow[j + 3] * S[j + 3];
            }
            float yp = (yp0 + yp1) + (yp2 + yp3);
            yp += __shfl_xor(yp, 1, 64);
            yp += __shfl_xor(yp, 2, 64);
            if (q == 0)
                y[(size_t)(t0 + i) * INTER + h * HP + p] = yp + Dh * xs[i][p];
        }
    }
}

// ---------------------------------------------------------------------------
// g = y * silu(gate); rmsnorm; g *= norm_w   (in place on y, fp32)
// ---------------------------------------------------------------------------
__global__ __launch_bounds__(256) void norm_kernel(float* __restrict__ y,
                                                   const float* __restrict__ gate,
                                                   const float* __restrict__ norm_w) {
    int t = blockIdx.x, tid = threadIdx.x;
    float* yrow = y + (size_t)t * INTER;
    const float* grow = gate + (size_t)t * INTER;
    float gv[16];
    float ss = 0.f;
#pragma unroll
    for (int i = 0; i < 16; i++) {
        int j = tid + i * 256;
        float ga = grow[j];
        float val = yrow[j] * (ga / (1.f + expf(-ga)));
        gv[i] = val;
        ss += val * val;
    }
#pragma unroll
    for (int off = 32; off > 0; off >>= 1) ss += __shfl_down(ss, off, 64);
    __shared__ float red[4];
    if ((tid & 63) == 0) red[tid >> 6] = ss;
    __syncthreads();
    float tot = red[0] + red[1] + red[2] + red[3];
    float scale = 1.0f / sqrtf(tot / (float)INTER + EPSV);
#pragma unroll
    for (int i = 0; i < 16; i++) {
        int j = tid + i * 256;
        yrow[j] = norm_w[j] * gv[i] * scale;
    }
}

// ---------------------------------------------------------------------------
// GEMM2: out = normed[LQ][INTER] @ out_proj_w[HID][INTER]^T -> fp32 (d_out!)
// ---------------------------------------------------------------------------
__global__ __launch_bounds__(256) void gemm2(const float* __restrict__ A,
                                             const float* __restrict__ B,
                                             float* __restrict__ C) {
    __shared__ float As[16][68];
    __shared__ float Bs[16][68];
    const int tx = threadIdx.x, ty = threadIdx.y;
    const int tid = ty * 16 + tx;
    const int m0 = blockIdx.y * 64, n0 = blockIdx.x * 64;
    const int lk = tid & 15, lr = tid >> 4;
    const int K = INTER;

    float acc[4][4] = {};
    for (int k0 = 0; k0 < K; k0 += 16) {
#pragma unroll
        for (int i = 0; i < 4; i++) {
            As[lk][lr + i * 16] = A[(size_t)(m0 + lr + i * 16) * K + k0 + lk];
            Bs[lk][lr + i * 16] = B[(size_t)(n0 + lr + i * 16) * K + k0 + lk];
        }
        __syncthreads();
#pragma unroll
        for (int k = 0; k < 16; k++) {
            float4 a4 = *(const float4*)&As[k][ty * 4];
            float4 b4 = *(const float4*)&Bs[k][tx * 4];
            float av[4] = {a4.x, a4.y, a4.z, a4.w};
            float bv[4] = {b4.x, b4.y, b4.z, b4.w};
#pragma unroll
            for (int i = 0; i < 4; i++)
#pragma unroll
                for (int j = 0; j < 4; j++) acc[i][j] += av[i] * bv[j];
        }
        __syncthreads();
    }
#pragma unroll
    for (int i = 0; i < 4; i++) {
        float4 o = make_float4(acc[i][0], acc[i][1], acc[i][2], acc[i][3]);
        *(float4*)&C[(size_t)(m0 + ty * 4 + i) * HID + n0 + tx * 4] = o;
    }
}

// ---------------------------------------------------------------------------
extern "C" void kernel_launch(void* const* d_in, const int* in_sizes, int n_in,
                              void* d_out, int out_size, void* d_ws, size_t ws_size,
                              hipStream_t stream) {
    const float* hidden     = (const float*)d_in[0];
    const float* in_proj_w  = (const float*)d_in[1];
    const float* conv_w     = (const float*)d_in[2];
    const float* conv_b     = (const float*)d_in[3];
    const float* A_log      = (const float*)d_in[4];
    const float* Dv         = (const float*)d_in[5];
    const float* dt_bias    = (const float*)d_in[6];
    const float* norm_w     = (const float*)d_in[7];
    const float* out_proj_w = (const float*)d_in[8];

    // Workspace layout, ~203 MiB (known to fit: ran in rounds 2-4):
    char* w = (char*)d_ws;
    float* gate   = (float*)w; w += (size_t)LQ * INTER * 4;      // 64 MiB
    float* convIn = (float*)w; w += (size_t)LQ * CONV_DIM * 4;   // 68 MiB
    float* hBC    = (float*)w; w += (size_t)LQ * CONV_DIM * 4;   // 68 MiB
    float* dtraw  = (float*)w; w += (size_t)LQ * NH * 4;         // 1 MiB
    float* dtg    = (float*)w; w += (size_t)LQ * NH * 4;         // 1 MiB
    float* dAg    = (float*)w;                                   // 1 MiB
    float* ybuf   = convIn;   // convIn dead after conv_silu; alias for y

    dim3 b16(16, 16);
    gemm1<<<dim3(PROJ_D / 64, LQ / 64), b16, 0, stream>>>(hidden, in_proj_w, gate, convIn, dtraw);
    conv_silu<<<(LQ * CONV_DIM) / 256, 256, 0, stream>>>(convIn, conv_w, conv_b, hBC);
    dt_kernel<<<(LQ * NH) / 256, 256, 0, stream>>>(dtraw, dt_bias, A_log, dtg, dAg);
    ssd_recur<<<NH, 256, 0, stream>>>(hBC, dtg, dAg, Dv, ybuf);
    norm_kernel<<<LQ, 256, 0, stream>>>(ybuf, gate, norm_w);
    gemm2<<<dim3(HID / 64, LQ / 64), b16, 0, stream>>>(ybuf, out_proj_w, (float*)d_out);
}

// Round 7
// 3595.598 us; speedup vs baseline: 1.3939x; 1.3939x over previous
//
#include <hip/hip_runtime.h>
#include <hip/hip_bf16.h>

typedef __hip_bfloat16 bf16;
typedef __attribute__((ext_vector_type(8))) short short8v;   // 8 bf16
typedef __attribute__((ext_vector_type(4))) float f32x4;

#define HID 2048
#define NH 64       // heads
#define HP 64       // head dim P
#define SN 128      // state dim N
#define KC 4        // conv kernel
#define CS 256      // chunk size
#define LQ 4096     // sequence length
#define INTER 4096
#define CONV_DIM 4352   // INTER + 2*G*N
#define PROJ_D 8512     // INTER + CONV_DIM + NH
#define NC 16           // LQ/CS
#define EPSV 1e-6f
#define BK 32

__device__ __forceinline__ float b2f(bf16 v) { return __bfloat162float(v); }
__device__ __forceinline__ bf16  f2b(float v) { return __float2bfloat16(v); }
__device__ __forceinline__ float s2f(short s) { union { short s; bf16 b; } u; u.s = s; return __bfloat162float(u.b); }
__device__ __forceinline__ short f2s(float x) { union { short s; bf16 b; } u; u.b = __float2bfloat16(x); return u.s; }
__device__ __forceinline__ short8v cvt8(float4 a, float4 b) {
    short8v v;
    v[0] = f2s(a.x); v[1] = f2s(a.y); v[2] = f2s(a.z); v[3] = f2s(a.w);
    v[4] = f2s(b.x); v[5] = f2s(b.y); v[6] = f2s(b.z); v[7] = f2s(b.w);
    return v;
}

// ---------------------------------------------------------------------------
// GEMM1 (bf16 MFMA, fp32 sources converted on the fly):
//   proj = hidden[LQ][HID] @ in_proj_w[PROJ_D][HID]^T
//   cols [0,4096) -> gate (bf16) ; [4096,8448) -> convIn (fp32)
//   dt columns [8448,8512) are NOT computed here (see dtexact).
// 128x128 tile, BK=32, 4 waves (2x2), wave = 64x64 = 4x4 frags of 16x16x32.
// ---------------------------------------------------------------------------
#define MFMA_STEP()                                                              \
    do {                                                                         \
        short8v af[4], bq[4];                                                    \
        _Pragma("unroll") for (int i = 0; i < 4; i++)                            \
            af[i] = *(const short8v*)&As[(wm * 64 + i * 16 + l15) * 40 + kg * 8];\
        _Pragma("unroll") for (int j = 0; j < 4; j++)                            \
            bq[j] = *(const short8v*)&Bs[(wn * 64 + j * 16 + l15) * 40 + kg * 8];\
        _Pragma("unroll") for (int i = 0; i < 4; i++)                            \
            _Pragma("unroll") for (int j = 0; j < 4; j++)                        \
                acc[i][j] = __builtin_amdgcn_mfma_f32_16x16x32_bf16(             \
                    af[i], bq[j], acc[i][j], 0, 0, 0);                           \
    } while (0)

#define STAGE_WRITE()                                                            \
    do {                                                                         \
        *(short8v*)&As[row0 * 40 + quad * 8] = ra0;                              \
        *(short8v*)&As[(row0 + 64) * 40 + quad * 8] = ra1;                       \
        *(short8v*)&Bs[row0 * 40 + quad * 8] = rb0;                              \
        *(short8v*)&Bs[(row0 + 64) * 40 + quad * 8] = rb1;                       \
    } while (0)

__global__ __launch_bounds__(256) void gemm1_mfma(const float* __restrict__ A,
                                                  const float* __restrict__ B,
                                                  bf16* __restrict__ gate,
                                                  float* __restrict__ convIn) {
    __shared__ short As[128 * 40];
    __shared__ short Bs[128 * 40];
    const int tid = threadIdx.x;
    const int lane = tid & 63, wid = tid >> 6;
    const int wm = wid >> 1, wn = wid & 1;
    const int l15 = lane & 15, kg = lane >> 4;
    const int m0 = blockIdx.y * 128, n0 = blockIdx.x * 128;
    const int row0 = tid >> 2, quad = tid & 3;
    const f32x4 z4 = {0.f, 0.f, 0.f, 0.f};
    f32x4 acc[4][4];
#pragma unroll
    for (int i = 0; i < 4; i++)
#pragma unroll
        for (int j = 0; j < 4; j++) acc[i][j] = z4;

    short8v ra0, ra1, rb0, rb1;
    auto LOAD = [&](int k0) {
        const float* ap0 = &A[(size_t)(m0 + row0) * HID + k0 + quad * 8];
        const float* ap1 = &A[(size_t)(m0 + row0 + 64) * HID + k0 + quad * 8];
        const float* bp0 = &B[(size_t)(n0 + row0) * HID + k0 + quad * 8];
        const float* bp1 = &B[(size_t)(n0 + row0 + 64) * HID + k0 + quad * 8];
        ra0 = cvt8(*(const float4*)ap0, *(const float4*)(ap0 + 4));
        ra1 = cvt8(*(const float4*)ap1, *(const float4*)(ap1 + 4));
        rb0 = cvt8(*(const float4*)bp0, *(const float4*)(bp0 + 4));
        rb1 = cvt8(*(const float4*)bp1, *(const float4*)(bp1 + 4));
    };

    LOAD(0);
    for (int k0 = 0; k0 < HID; k0 += BK) {
        __syncthreads();
        STAGE_WRITE();
        __syncthreads();
        if (k0 + BK < HID) LOAD(k0 + BK);
        MFMA_STEP();
    }
    const int rbase = m0 + wm * 64 + kg * 4;
#pragma unroll
    for (int i = 0; i < 4; i++)
#pragma unroll
        for (int j = 0; j < 4; j++) {
            int col = n0 + wn * 64 + j * 16 + l15;
#pragma unroll
            for (int r = 0; r < 4; r++) {
                int row = rbase + i * 16 + r;
                float v = acc[i][j][r];
                if (col < INTER) gate[(size_t)row * INTER + col] = f2b(v);
                else convIn[(size_t)row * CONV_DIM + (col - INTER)] = v;
            }
        }
}

// ---------------------------------------------------------------------------
// GEMM2 (bf16 MFMA): out = normed[LQ][INTER](bf16) @ out_proj_w[HID][INTER]^T
// (fp32 weight converted on the fly) -> fp32 d_out
// ---------------------------------------------------------------------------
__global__ __launch_bounds__(256) void gemm2_mfma(const bf16* __restrict__ A,
                                                  const float* __restrict__ B,
                                                  float* __restrict__ C) {
    __shared__ short As[128 * 40];
    __shared__ short Bs[128 * 40];
    const int tid = threadIdx.x;
    const int lane = tid & 63, wid = tid >> 6;
    const int wm = wid >> 1, wn = wid & 1;
    const int l15 = lane & 15, kg = lane >> 4;
    const int m0 = blockIdx.y * 128, n0 = blockIdx.x * 128;
    const int row0 = tid >> 2, quad = tid & 3;
    const f32x4 z4 = {0.f, 0.f, 0.f, 0.f};
    f32x4 acc[4][4];
#pragma unroll
    for (int i = 0; i < 4; i++)
#pragma unroll
        for (int j = 0; j < 4; j++) acc[i][j] = z4;

    short8v ra0, ra1, rb0, rb1;
    auto LOAD = [&](int k0) {
        ra0 = *(const short8v*)&A[(size_t)(m0 + row0) * INTER + k0 + quad * 8];
        ra1 = *(const short8v*)&A[(size_t)(m0 + row0 + 64) * INTER + k0 + quad * 8];
        const float* bp0 = &B[(size_t)(n0 + row0) * INTER + k0 + quad * 8];
        const float* bp1 = &B[(size_t)(n0 + row0 + 64) * INTER + k0 + quad * 8];
        rb0 = cvt8(*(const float4*)bp0, *(const float4*)(bp0 + 4));
        rb1 = cvt8(*(const float4*)bp1, *(const float4*)(bp1 + 4));
    };

    LOAD(0);
    for (int k0 = 0; k0 < INTER; k0 += BK) {
        __syncthreads();
        STAGE_WRITE();
        __syncthreads();
        if (k0 + BK < INTER) LOAD(k0 + BK);
        MFMA_STEP();
    }
    const int rbase = m0 + wm * 64 + kg * 4;
#pragma unroll
    for (int i = 0; i < 4; i++)
#pragma unroll
        for (int j = 0; j < 4; j++) {
            int col = n0 + wn * 64 + j * 16 + l15;
#pragma unroll
            for (int r = 0; r < 4; r++)
                C[(size_t)(rbase + i * 16 + r) * HID + col] = acc[i][j][r];
        }
}

// ---------------------------------------------------------------------------
// dtexact: dtraw[t][h] = dot(hidden[t,:], in_proj_w[8448+h,:]) in pure fp32.
// Block = 8 t-rows staged in LDS; thread (h = tid>>2, q = tid&3) does k==q mod 4.
// ---------------------------------------------------------------------------
__global__ __launch_bounds__(256) void dtexact(const float* __restrict__ hidden,
                                               const float* __restrict__ W,
                                               float* __restrict__ dtraw) {
    __shared__ float hs[8][HID];   // 64 KiB
    int t0 = blockIdx.x * 8;
    int tid = threadIdx.x;
    for (int i = tid; i < 8 * HID; i += 256) {
        int r = i >> 11, k = i & (HID - 1);
        hs[r][k] = hidden[(size_t)(t0 + r) * HID + k];
    }
    __syncthreads();
    int h = tid >> 2, q = tid & 3;
    const float* wrow = W + (size_t)(INTER + CONV_DIM + h) * HID;
    float acc[8] = {};
    for (int j = 0; j < HID / 4; j++) {
        int k = q + 4 * j;
        float wv = wrow[k];
#pragma unroll
        for (int r = 0; r < 8; r++) acc[r] += wv * hs[r][k];
    }
#pragma unroll
    for (int r = 0; r < 8; r++) {
        acc[r] += __shfl_xor(acc[r], 1, 64);
        acc[r] += __shfl_xor(acc[r], 2, 64);
    }
    if (q == 0) {
#pragma unroll
        for (int r = 0; r < 8; r++)
            dtraw[(size_t)(t0 + r) * NH + h] = acc[r];
    }
}

// ---------------------------------------------------------------------------
// Depthwise causal conv (K=4) + bias + silu.  fp32 in -> x (bf16) + BC (fp32).
// ---------------------------------------------------------------------------
__global__ __launch_bounds__(256) void conv_silu(const float* __restrict__ convIn,
                                                 const float* __restrict__ cw,
                                                 const float* __restrict__ cb,
                                                 bf16* __restrict__ xb,
                                                 float* __restrict__ BCf) {
    int id = blockIdx.x * 256 + threadIdx.x;      // LQ*CONV_DIM, c fastest
    int c = id % CONV_DIM;
    int t = id / CONV_DIM;
    float acc = cb[c];
#pragma unroll
    for (int j = 0; j < KC; j++) {
        int tt = t - (KC - 1) + j;
        if (tt >= 0) acc += convIn[(size_t)tt * CONV_DIM + c] * cw[c * KC + j];
    }
    float sv = acc / (1.f + expf(-acc));
    if (c < INTER) xb[(size_t)t * INTER + c] = f2b(sv);
    else BCf[(size_t)t * (2 * SN) + (c - INTER)] = sv;
}

// ---------------------------------------------------------------------------
// dt = softplus(dtraw + dt_bias); Acum = chunk-local cumsum(dt * A)
// ---------------------------------------------------------------------------
__global__ void dt_kernel(const float* __restrict__ dtraw,
                          const float* __restrict__ dt_bias,
                          const float* __restrict__ A_log,
                          float* __restrict__ dtg,     // [LQ][NH]
                          float* __restrict__ Acum) {  // [NC][NH][CS]
    int c = blockIdx.x, h = threadIdx.x;
    float A = -expf(A_log[h]);
    float bias = dt_bias[h];
    float run = 0.f;
    for (int s = 0; s < CS; s++) {
        int t = c * CS + s;
        float x = dtraw[(size_t)t * NH + h] + bias;
        float dtv = (x > 20.f) ? x : log1pf(expf(x));
        dtg[(size_t)t * NH + h] = dtv;
        run += dtv * A;
        Acum[((size_t)c * NH + h) * CS + s] = run;
    }
}

// ---------------------------------------------------------------------------
// CB[c][s][z] = sum_n C[c,s,n]*B[c,z,n]  (G=1: shared across all heads)
// ---------------------------------------------------------------------------
__global__ __launch_bounds__(256) void cb_kernel(const float* __restrict__ BCf,
                                                 float* __restrict__ CB) {
    int sblk = blockIdx.x, c = blockIdx.y;
    int tx = threadIdx.x, ty = threadIdx.y;
    int tid = ty * 16 + tx;
    __shared__ float Cs[16][132];
    __shared__ float Bsl[16][132];
    int s0 = sblk * 16;
    for (int i = tid; i < 16 * SN; i += 256) {
        int r = i >> 7, n = i & 127;
        Cs[r][n] = BCf[(size_t)(c * CS + s0 + r) * (2 * SN) + SN + n];
    }
    for (int zt = 0; zt < 16; zt++) {
        __syncthreads();
        for (int i = tid; i < 16 * SN; i += 256) {
            int r = i >> 7, n = i & 127;
            Bsl[r][n] = BCf[(size_t)(c * CS + zt * 16 + r) * (2 * SN) + n];
        }
        __syncthreads();
        float acc = 0.f;
#pragma unroll 4
        for (int n = 0; n < SN; n += 4) {
            float4 c4 = *(const float4*)&Cs[ty][n];
            float4 b4 = *(const float4*)&Bsl[tx][n];
            acc += c4.x * b4.x + c4.y * b4.y + c4.z * b4.z + c4.w * b4.w;
        }
        CB[((size_t)(c * CS + s0 + ty)) * CS + zt * 16 + tx] = acc;
    }
}

// ---------------------------------------------------------------------------
// states[c][h][p][n] = sum_z B[z,n]*exp(Ac[255]-Ac[z])*dt[z]*x[z,h,p]  (fp32)
// ---------------------------------------------------------------------------
__global__ __launch_bounds__(256) void states_kernel(const bf16* __restrict__ xb,
                                                     const float* __restrict__ BCf,
                                                     const float* __restrict__ dtg,
                                                     const float* __restrict__ Acum,
                                                     float* __restrict__ states) {
    int h = blockIdx.x, c = blockIdx.y;
    int tid = threadIdx.x;
    __shared__ float xw[64][68];
    __shared__ float Bsh[64][SN];
    __shared__ float wz[64];
    const float* Ac = Acum + ((size_t)c * NH + h) * CS;
    float Alast = Ac[CS - 1];
    float acc[32] = {};
    int p = tid >> 2;
    int n0 = (tid & 3) * 32;
    for (int zt = 0; zt < 4; zt++) {
        __syncthreads();
        if (tid < 64) {
            int z = zt * 64 + tid;
            wz[tid] = expf(Alast - Ac[z]) * dtg[(size_t)(c * CS + z) * NH + h];
        }
        __syncthreads();
        for (int i = tid; i < 64 * 64; i += 256) {
            int zl = i >> 6, pp = i & 63;
            xw[zl][pp] = b2f(xb[(size_t)(c * CS + zt * 64 + zl) * INTER + h * HP + pp]) * wz[zl];
        }
        for (int i = tid; i < 64 * SN; i += 256) {
            int zl = i >> 7, nn = i & 127;
            Bsh[zl][nn] = BCf[(size_t)(c * CS + zt * 64 + zl) * (2 * SN) + nn];
        }
        __syncthreads();
        for (int zl = 0; zl < 64; zl++) {
            float xv = xw[zl][p];
            const float4* brow = (const float4*)&Bsh[zl][n0];
#pragma unroll
            for (int j = 0; j < 8; j++) {
                float4 b4 = brow[j];
                acc[j * 4 + 0] += xv * b4.x;
                acc[j * 4 + 1] += xv * b4.y;
                acc[j * 4 + 2] += xv * b4.z;
                acc[j * 4 + 3] += xv * b4.w;
            }
        }
    }
    float* sp = states + (((size_t)(c * NH + h) * HP + p) * SN) + n0;
#pragma unroll
    for (int j = 0; j < 8; j++)
        ((float4*)sp)[j] = make_float4(acc[j * 4], acc[j * 4 + 1], acc[j * 4 + 2], acc[j * 4 + 3]);
}

// ---------------------------------------------------------------------------
// inter-chunk scan: prev[c]=carry-before; carry = carry*exp(Acum[c][255])+states[c]
// ---------------------------------------------------------------------------
__global__ __launch_bounds__(256) void scan_kernel(const float* __restrict__ states,
                                                   const float* __restrict__ Acum,
                                                   float* __restrict__ prev) {
    int g = blockIdx.x * 256 + threadIdx.x;   // NH*HP*SN
    int n = g & 127, p = (g >> 7) & 63, h = g >> 13;
    float carry = 0.f;
    for (int c = 0; c < NC; c++) {
        size_t idx = (((size_t)(c * NH + h) * HP + p) * SN) + n;
        prev[idx] = carry;
        float cd = expf(Acum[((size_t)c * NH + h) * CS + CS - 1]);
        carry = carry * cd + states[idx];
    }
}

// ---------------------------------------------------------------------------
// y[t][h*64+p] = Y_diag + Y_off + D[h]*x ; block per (h,c), thread = s. fp32 out.
// ---------------------------------------------------------------------------
__global__ __launch_bounds__(256) void y_kernel(const bf16* __restrict__ xb,
                                                const float* __restrict__ BCf,
                                                const float* __restrict__ dtg,
                                                const float* __restrict__ Acum,
                                                const float* __restrict__ CB,
                                                const float* __restrict__ prev,
                                                const float* __restrict__ Dv,
                                                float* __restrict__ y) {
    int h = blockIdx.x, c = blockIdx.y;
    int s = threadIdx.x;
    __shared__ float xt[64][68];
    __shared__ float pv[HP][SN];
    __shared__ float Acs[CS];
    __shared__ float dts[CS];
    Acs[s] = Acum[((size_t)c * NH + h) * CS + s];
    dts[s] = dtg[(size_t)(c * CS + s) * NH + h];
    __syncthreads();
    float myAc = Acs[s];
    float acc[64] = {};
    const float* cbrow = CB + (size_t)(c * CS + s) * CS;

    // Y_diag
    for (int zt = 0; zt < 4; zt++) {
        __syncthreads();
        for (int i = s; i < 64 * 64; i += 256) {
            int zl = i >> 6, pp = i & 63;
            xt[zl][pp] = b2f(xb[(size_t)(c * CS + zt * 64 + zl) * INTER + h * HP + pp]);
        }
        __syncthreads();
        if (zt * 64 <= s) {
            for (int zl0 = 0; zl0 < 64; zl0 += 4) {
                int z0 = zt * 64 + zl0;
                if (z0 > s) break;
                float4 cb4 = *(const float4*)(cbrow + z0);
                float cbv[4] = {cb4.x, cb4.y, cb4.z, cb4.w};
#pragma unroll
                for (int k = 0; k < 4; k++) {
                    int z = z0 + k;
                    if (z > s) break;
                    float wv = cbv[k] * expf(myAc - Acs[z]) * dts[z];
                    const float4* xr = (const float4*)&xt[z - zt * 64][0];
#pragma unroll
                    for (int q = 0; q < 16; q++) {
                        float4 x4 = xr[q];
                        acc[q * 4 + 0] += wv * x4.x;
                        acc[q * 4 + 1] += wv * x4.y;
                        acc[q * 4 + 2] += wv * x4.z;
                        acc[q * 4 + 3] += wv * x4.w;
                    }
                }
            }
        }
    }

    // Y_off: exp(Ac[s]) * sum_n C[s][n] * prev[h][p][n]
    __syncthreads();
    for (int i = s; i < HP * SN; i += 256) {
        int pp = i >> 7, nn = i & 127;
        pv[pp][nn] = prev[(((size_t)(c * NH + h) * HP) + pp) * SN + nn];
    }
    __syncthreads();
    float eAs = expf(myAc);
    const float* crow = BCf + (size_t)(c * CS + s) * (2 * SN) + SN;
    for (int nn = 0; nn < SN; nn += 4) {
        float4 c4 = *(const float4*)(crow + nn);
        float c0 = c4.x * eAs, c1 = c4.y * eAs, c2 = c4.z * eAs, c3 = c4.w * eAs;
#pragma unroll 16
        for (int pp = 0; pp < HP; pp++) {
            float4 p4 = *(const float4*)&pv[pp][nn];
            acc[pp] += c0 * p4.x + c1 * p4.y + c2 * p4.z + c3 * p4.w;
        }
    }

    // + D*x, write fp32
    float Dh = Dv[h];
    const bf16* xrow = xb + (size_t)(c * CS + s) * INTER + h * HP;
    float* yrow = y + (size_t)(c * CS + s) * INTER + h * HP;
#pragma unroll
    for (int pp = 0; pp < HP; pp++)
        yrow[pp] = acc[pp] + Dh * b2f(xrow[pp]);
}

// ---------------------------------------------------------------------------
// g = y(fp32) * silu(gate bf16); rmsnorm; *= norm_w -> ybuf (bf16)
// ---------------------------------------------------------------------------
__global__ __launch_bounds__(256) void norm_kernel(const float* __restrict__ y,
                                                   const bf16* __restrict__ gate,
                                                   const float* __restrict__ norm_w,
                                                   bf16* __restrict__ outp) {
    int t = blockIdx.x, tid = threadIdx.x;
    const float4* y4 = (const float4*)(y + (size_t)t * INTER);
    const short8v* g8 = (const short8v*)(gate + (size_t)t * INTER);
    float gv[16];
    float ss = 0.f;
#pragma unroll
    for (int i = 0; i < 2; i++) {
        int idx = i * 256 + tid;
        short8v gvv = g8[idx];
        float4 ya = y4[2 * idx], yb = y4[2 * idx + 1];
        float yv[8] = {ya.x, ya.y, ya.z, ya.w, yb.x, yb.y, yb.z, yb.w};
#pragma unroll
        for (int e = 0; e < 8; e++) {
            float ga = s2f(gvv[e]);
            float val = yv[e] * (ga / (1.f + expf(-ga)));
            gv[i * 8 + e] = val;
            ss += val * val;
        }
    }
#pragma unroll
    for (int off = 32; off > 0; off >>= 1) ss += __shfl_down(ss, off, 64);
    __shared__ float red[4];
    if ((tid & 63) == 0) red[tid >> 6] = ss;
    __syncthreads();
    float tot = red[0] + red[1] + red[2] + red[3];
    float scale = 1.0f / sqrtf(tot / (float)INTER + EPSV);
    short8v* o8 = (short8v*)(outp + (size_t)t * INTER);
#pragma unroll
    for (int i = 0; i < 2; i++) {
        int idx = i * 256 + tid;
        short8v ov;
#pragma unroll
        for (int e = 0; e < 8; e++)
            ov[e] = f2s(norm_w[idx * 8 + e] * gv[i * 8 + e] * scale);
        o8[idx] = ov;
    }
}

// ---------------------------------------------------------------------------
extern "C" void kernel_launch(void* const* d_in, const int* in_sizes, int n_in,
                              void* d_out, int out_size, void* d_ws, size_t ws_size,
                              hipStream_t stream) {
    const float* hidden     = (const float*)d_in[0];
    const float* in_proj_w  = (const float*)d_in[1];
    const float* conv_w     = (const float*)d_in[2];
    const float* conv_b     = (const float*)d_in[3];
    const float* A_log      = (const float*)d_in[4];
    const float* Dv         = (const float*)d_in[5];
    const float* dt_bias    = (const float*)d_in[6];
    const float* norm_w     = (const float*)d_in[7];
    const float* out_proj_w = (const float*)d_in[8];

    // Workspace: 204 MiB total
    char* w = (char*)d_ws;
    bf16*  gate_b = (bf16*)w;  w += (size_t)LQ * INTER * 2;         // 32 MiB
    bf16*  x_b    = (bf16*)w;  w += (size_t)LQ * INTER * 2;         // 32 MiB
    float* BCf    = (float*)w; w += (size_t)LQ * 2 * SN * 4;        //  4 MiB
    float* CBuf   = (float*)w; w += (size_t)NC * CS * CS * 4;       //  4 MiB
    float* prev   = (float*)w; w += (size_t)NC * NH * HP * SN * 4;  // 32 MiB
    char*  R1     = w;         w += (size_t)NC * NH * HP * SN * 4;  // 32 MiB
    char*  R2     = w;         w += (size_t)LQ * CONV_DIM * 4;      // 68 MiB
    // R1 phases: dtraw (phases 1-2) -> states (phase 3) -> ybuf_b (phases 5-6)
    float* dtraw  = (float*)R1;
    float* states = (float*)R1;
    bf16*  ybuf_b = (bf16*)R1;
    // R2 phases: convIn (phases 1-2) -> y fp32 [0,64M) + dtg/Acum [64,66M)
    float* convIn = (float*)R2;
    float* yf     = (float*)R2;
    float* dtg    = (float*)(R2 + (size_t)64 * 1024 * 1024);
    float* Acum   = (float*)(R2 + (size_t)65 * 1024 * 1024);

    gemm1_mfma<<<dim3(66, 32), 256, 0, stream>>>(hidden, in_proj_w, gate_b, convIn);
    dtexact<<<LQ / 8, 256, 0, stream>>>(hidden, in_proj_w, dtraw);
    conv_silu<<<(LQ * CONV_DIM) / 256, 256, 0, stream>>>(convIn, conv_w, conv_b, x_b, BCf);
    dt_kernel<<<NC, NH, 0, stream>>>(dtraw, dt_bias, A_log, dtg, Acum);
    cb_kernel<<<dim3(16, NC), dim3(16, 16), 0, stream>>>(BCf, CBuf);
    states_kernel<<<dim3(NH, NC), 256, 0, stream>>>(x_b, BCf, dtg, Acum, states);
    scan_kernel<<<(NH * HP * SN) / 256, 256, 0, stream>>>(states, Acum, prev);
    y_kernel<<<dim3(NH, NC), 256, 0, stream>>>(x_b, BCf, dtg, Acum, CBuf, prev, Dv, yf);
    norm_kernel<<<LQ, 256, 0, stream>>>(yf, gate_b, norm_w, ybuf_b);
    gemm2_mfma<<<dim3(16, 32), 256, 0, stream>>>(ybuf_b, out_proj_w, (float*)d_out);
}